// Round 1
// baseline (351.645 us; speedup 1.0000x reference)
//
#include <hip/hip_runtime.h>
#include <stdint.h>

#define T_TOK 2048
#define D_DIM 1024
#define H_DIM 2048
#define N_EXP 8
#define MAXS  5120   // max padded slots: 4096 + 8*127 = 5112 -> 5120

// workspace layout (bytes)
#define WS_CNT    0
#define WS_BTOK   256
#define WS_BW     (WS_BTOK + N_EXP*2048*4)
#define WS_XG     (WS_BW + N_EXP*2048*4)        // 16B aligned
#define WS_HBUF   (WS_XG + (size_t)MAXS*1024*2)
#define WS_W1T    (WS_HBUF + (size_t)MAXS*2048*2)
#define WS_W2T    (WS_W1T + (size_t)N_EXP*1024*2048*2)

typedef __bf16 bf16x8 __attribute__((ext_vector_type(8)));
typedef float  f32x4  __attribute__((ext_vector_type(4)));

__device__ __forceinline__ unsigned short f2bf(float f) {
  unsigned int u = __float_as_uint(f);
  u += 0x7fffu + ((u >> 16) & 1u);   // round-to-nearest-even
  return (unsigned short)(u >> 16);
}

__device__ __forceinline__ float gelu_tanh(float x) {
  float u = 0.7978845608028654f * (x + 0.044715f * x * x * x);
  return 0.5f * x * (1.0f + tanhf(u));
}

__global__ void zero_kernel(float4* __restrict__ out4, int* __restrict__ cnt) {
  int i = blockIdx.x * 256 + threadIdx.x;  // 2048 blocks * 256 * 4 floats = T*D
  out4[i] = make_float4(0.f, 0.f, 0.f, 0.f);
  if (blockIdx.x == 0 && threadIdx.x < N_EXP) cnt[threadIdx.x] = 0;
}

// one wave per token: logits = x @ Wg + bg; top-2; softmax; bucket scatter
__global__ void gate_kernel(const float* __restrict__ x, const float* __restrict__ Wg,
                            const float* __restrict__ bg, float* __restrict__ out_idx,
                            int* __restrict__ cnt, int* __restrict__ btok,
                            float* __restrict__ bw) {
  const int lane = threadIdx.x & 63;
  const int t = blockIdx.x * 4 + (threadIdx.x >> 6);
  float p[8];
#pragma unroll
  for (int i = 0; i < 8; ++i) p[i] = 0.f;
  const float* xr = x + (size_t)t * D_DIM;
  for (int i = lane; i < D_DIM; i += 64) {
    const float xv = xr[i];
    const float4 wa = ((const float4*)(Wg + i * 8))[0];
    const float4 wb = ((const float4*)(Wg + i * 8))[1];
    p[0] += xv * wa.x; p[1] += xv * wa.y; p[2] += xv * wa.z; p[3] += xv * wa.w;
    p[4] += xv * wb.x; p[5] += xv * wb.y; p[6] += xv * wb.z; p[7] += xv * wb.w;
  }
#pragma unroll
  for (int off = 32; off > 0; off >>= 1) {
#pragma unroll
    for (int i = 0; i < 8; ++i) p[i] += __shfl_xor(p[i], off);
  }
  if (lane == 0) {
#pragma unroll
    for (int i = 0; i < 8; ++i) p[i] += bg[i];
    int i0 = 0; float v0 = p[0];
#pragma unroll
    for (int i = 1; i < 8; ++i) if (p[i] > v0) { v0 = p[i]; i0 = i; }
    int i1 = -1; float v1 = -3.4e38f;
#pragma unroll
    for (int i = 0; i < 8; ++i) if (i != i0 && p[i] > v1) { v1 = p[i]; i1 = i; }
    const float ex = expf(v1 - v0);
    const float inv = 1.f / (1.f + ex);
    out_idx[t * 2 + 0] = (float)i0;
    out_idx[t * 2 + 1] = (float)i1;
    int s0 = atomicAdd(&cnt[i0], 1);
    btok[i0 * 2048 + s0] = t; bw[i0 * 2048 + s0] = inv;
    int s1 = atomicAdd(&cnt[i1], 1);
    btok[i1 * 2048 + s1] = t; bw[i1 * 2048 + s1] = ex * inv;
  }
}

// Both weight transposes in one launch. set 0: W1 [e][1024][2048] -> [e][2048][1024]
//                                      set 1: W2 [e][2048][1024] -> [e][1024][2048]
__global__ void transpose_cvt(const float* __restrict__ W1, unsigned short* __restrict__ W1t,
                              const float* __restrict__ W2, unsigned short* __restrict__ W2t) {
  const int set = blockIdx.z;
  const int e = blockIdx.y;
  const int lin = blockIdx.x;               // 0..511
  const int R = set ? H_DIM : D_DIM;
  const int C = set ? D_DIM : H_DIM;
  const int tx = set ? (lin & 15) : (lin & 31);
  const int ty = set ? (lin >> 4) : (lin >> 5);
  const float* in = (set ? W2 : W1) + (size_t)e * (D_DIM * H_DIM);
  unsigned short* out = (set ? W2t : W1t) + (size_t)e * (D_DIM * H_DIM);
  const int c0 = tx * 64, r0 = ty * 64;
  __shared__ float tile[64][68];
  const int tid = threadIdx.x;
#pragma unroll
  for (int p = 0; p < 4; ++p) {
    const int idx = p * 256 + tid;
    const int r = idx >> 4, c4 = idx & 15;
    *(float4*)&tile[r][c4 * 4] = *(const float4*)(in + (size_t)(r0 + r) * C + c0 + c4 * 4);
  }
  __syncthreads();
#pragma unroll
  for (int p = 0; p < 2; ++p) {
    const int idx = p * 256 + tid;
    const int oc = idx >> 3, seg = idx & 7;
    unsigned u[4];
#pragma unroll
    for (int j = 0; j < 4; ++j) {
      const unsigned lo = f2bf(tile[seg * 8 + 2 * j][oc]);
      const unsigned hi = f2bf(tile[seg * 8 + 2 * j + 1][oc]);
      u[j] = lo | (hi << 16);
    }
    *(uint4*)(out + (size_t)(c0 + oc) * R + r0 + seg * 8) = make_uint4(u[0], u[1], u[2], u[3]);
  }
}

// inline padded prefix over the 8 expert counts (pad to 128-row tiles)
__device__ __forceinline__ void expert_seg(const int* __restrict__ cnt, int e,
                                           int& base, int& ce, int& pcnt, int& total) {
  int off = 0; base = 0; ce = 0; pcnt = 0;
#pragma unroll
  for (int i = 0; i < N_EXP; ++i) {
    const int c = cnt[i];
    const int p = (c + 127) & ~127;
    if (i == e) { base = off; ce = c; pcnt = p; }
    off += p;
  }
  total = off;
}

// one block per padded slot row: gather routed token row fp32 -> bf16 (pad rows = 0)
__global__ void gather_cvt(const float* __restrict__ x, const int* __restrict__ cnt,
                           const int* __restrict__ btok, unsigned short* __restrict__ Xg) {
  const int s = blockIdx.x;
  int off = 0, e = -1, loc = 0, c_e = 0;
#pragma unroll
  for (int i = 0; i < N_EXP; ++i) {
    const int c = cnt[i];
    const int p = (c + 127) & ~127;
    if (e < 0 && s < off + p) { e = i; loc = s - off; c_e = c; }
    off += p;
  }
  if (e < 0) return;  // beyond total padded slots
  uint2* orow = (uint2*)(Xg + (size_t)s * D_DIM);
  if (loc < c_e) {
    const int t = btok[e * 2048 + loc];
    const float4 v = ((const float4*)(x + (size_t)t * D_DIM))[threadIdx.x];
    uint2 u;
    u.x = (unsigned)f2bf(v.x) | ((unsigned)f2bf(v.y) << 16);
    u.y = (unsigned)f2bf(v.z) | ((unsigned)f2bf(v.w) << 16);
    orow[threadIdx.x] = u;
  } else {
    orow[threadIdx.x] = make_uint2(0u, 0u);
  }
}

// MODE 0: Hbuf[s][n] = gelu(Xg[s] @ W1t[e]^T + b1[e])     (K=1024, N=2048, SK=1)
// MODE 1: out[tok]  += w_s * (Hbuf[s] @ W2t[e]^T + b2[e]) (K=2048, N=1024, SK=2, atomic)
// m97 structure: 128x128 tiles (4 waves 2x2, acc 4x4 each = 16 MFMA/K-step/wave),
// double-buffered LDS (32KB), one barrier/iter, global_load_lds width 16.
// Grid 2048, XCD-swizzled: all m-tiles of one (n,e,ksl) share blockIdx%8 -> one XCD
// so the 256KB B panel stays L2-local.
template <int MODE>
__global__ void __launch_bounds__(256) moe_gemm(
    const unsigned short* __restrict__ A, const unsigned short* __restrict__ B,
    const float* __restrict__ bias, const int* __restrict__ cnt,
    const int* __restrict__ btok, const float* __restrict__ bw,
    unsigned short* __restrict__ Hout, float* __restrict__ out) {
  constexpr int K   = (MODE == 0) ? D_DIM : H_DIM;
  constexpr int SK  = (MODE == 0) ? 1 : 2;
  constexpr int KS  = K / SK;
  constexpr int NIT = KS / 32;

  const int lin = blockIdx.x;                 // 0..2047
  const int glo = lin & 7;
  const int mt  = (lin >> 3) & 15;            // up to 16 m-tiles of 128 rows
  const int combo = ((lin >> 7) << 3) | glo;  // 0..127: (n,e,ksl), low 3 bits = XCD
  int nt, e, ksl;
  if (MODE == 0) { nt = combo & 15; e = combo >> 4; ksl = 0; }
  else           { nt = combo & 7;  e = (combo >> 3) & 7; ksl = combo >> 6; }

  int base, ce, pcnt, total;
  expert_seg(cnt, e, base, ce, pcnt, total);
  if (mt * 128 >= pcnt) return;
  const int row0 = base + mt * 128;
  const int n0 = nt * 128;

  __shared__ __align__(16) unsigned short As[2][128 * 32];
  __shared__ __align__(16) unsigned short Bs[2][128 * 32];

  const int tid = threadIdx.x;
  const int lane = tid & 63;
  const int wv = tid >> 6;
  const int wm = wv >> 1;
  const int wn = wv & 1;

  const unsigned short* Ab = A + (size_t)row0 * K + ksl * KS;
  const unsigned short* Bb = B + (size_t)e * ((size_t)H_DIM * D_DIM) + (size_t)n0 * K + ksl * KS;

  f32x4 acc[4][4];
#pragma unroll
  for (int i = 0; i < 4; ++i)
#pragma unroll
    for (int j = 0; j < 4; ++j) acc[i][j] = (f32x4)(0.0f);

  const int subr = lane >> 2;        // 0..15
  const int ks = (lane & 3) * 8;     // 0,8,16,24 halfs
  const int fr = lane & 15;
  const int kq = (lane >> 4) * 8;

  auto stage = [&](int kt, int b) {
    const int k0 = kt * 32;
#pragma unroll
    for (int it = 0; it < 2; ++it) {   // 8 chunks of 16 rows each for A and B; 2 per wave
      const int ci = wv * 2 + it;      // 0..7
      const int r = ci * 16 + subr;
      const unsigned short* ga = Ab + (size_t)r * K + (k0 + ks);
      __builtin_amdgcn_global_load_lds(
          (__attribute__((address_space(1))) void*)ga,
          (__attribute__((address_space(3))) void*)(As[b] + ci * 16 * 32), 16, 0, 0);
      const unsigned short* gb = Bb + (size_t)r * K + (k0 + ks);
      __builtin_amdgcn_global_load_lds(
          (__attribute__((address_space(1))) void*)gb,
          (__attribute__((address_space(3))) void*)(Bs[b] + ci * 16 * 32), 16, 0, 0);
    }
  };

  stage(0, 0);
  for (int i = 0; i < NIT; ++i) {
    const int b = i & 1;
    __syncthreads();                  // drains prefetch into buf b; protects WAR on b^1
    if (i + 1 < NIT) stage(i + 1, b ^ 1);
    bf16x8 av[4], bv[4];
#pragma unroll
    for (int mi = 0; mi < 4; ++mi)
      av[mi] = *(const bf16x8*)(As[b] + (wm * 64 + mi * 16 + fr) * 32 + kq);
#pragma unroll
    for (int ni = 0; ni < 4; ++ni)
      bv[ni] = *(const bf16x8*)(Bs[b] + (wn * 64 + ni * 16 + fr) * 32 + kq);
#pragma unroll
    for (int mi = 0; mi < 4; ++mi)
#pragma unroll
      for (int ni = 0; ni < 4; ++ni)
        acc[mi][ni] = __builtin_amdgcn_mfma_f32_16x16x32_bf16(av[mi], bv[ni], acc[mi][ni], 0, 0, 0);
  }

  if (MODE == 0) {
    const float* bb = bias + (size_t)e * H_DIM + n0;
#pragma unroll
    for (int mi = 0; mi < 4; ++mi) {
      const int rb = wm * 64 + mi * 16 + (lane >> 4) * 4;
#pragma unroll
      for (int r = 0; r < 4; ++r) {
        unsigned short* hp = Hout + (size_t)(row0 + rb + r) * H_DIM + n0;
#pragma unroll
        for (int ni = 0; ni < 4; ++ni) {
          const int col = wn * 64 + ni * 16 + fr;
          hp[col] = f2bf(gelu_tanh(acc[mi][ni][r] + bb[col]));
        }
      }
    }
  } else {
    const float* bb = bias + (size_t)e * D_DIM + n0;
#pragma unroll
    for (int mi = 0; mi < 4; ++mi) {
      const int rb = wm * 64 + mi * 16 + (lane >> 4) * 4;
#pragma unroll
      for (int r = 0; r < 4; ++r) {
        const int local = mt * 128 + rb + r;
        if (local < ce) {
          const int tok = btok[e * 2048 + local];
          const float w = bw[e * 2048 + local];
          float* op = out + (size_t)tok * D_DIM + n0;
#pragma unroll
          for (int ni = 0; ni < 4; ++ni) {
            const int col = wn * 64 + ni * 16 + fr;
            const float bias_once = (ksl == 0) ? bb[col] : 0.f;
            atomicAdd(op + col, w * (acc[mi][ni][r] + bias_once));
          }
        }
      }
    }
  }
}

extern "C" void kernel_launch(void* const* d_in, const int* in_sizes, int n_in,
                              void* d_out, int out_size, void* d_ws, size_t ws_size,
                              hipStream_t stream) {
  const float* moe_inp = (const float*)d_in[0];
  const float* Wg = (const float*)d_in[1];
  const float* bg = (const float*)d_in[2];
  const float* W1 = (const float*)d_in[3];
  const float* b1 = (const float*)d_in[4];
  const float* W2 = (const float*)d_in[5];
  const float* b2 = (const float*)d_in[6];
  float* out = (float*)d_out;

  char* ws = (char*)d_ws;
  int* cnt  = (int*)(ws + WS_CNT);
  int* btok = (int*)(ws + WS_BTOK);
  float* bw = (float*)(ws + WS_BW);
  unsigned short* Xg   = (unsigned short*)(ws + WS_XG);
  unsigned short* Hbuf = (unsigned short*)(ws + WS_HBUF);
  unsigned short* W1t  = (unsigned short*)(ws + WS_W1T);
  unsigned short* W2t  = (unsigned short*)(ws + WS_W2T);

  zero_kernel<<<dim3(2048), dim3(256), 0, stream>>>((float4*)out, cnt);
  gate_kernel<<<dim3(T_TOK / 4), dim3(256), 0, stream>>>(moe_inp, Wg, bg,
                                                         out + (size_t)T_TOK * D_DIM,
                                                         cnt, btok, bw);
  transpose_cvt<<<dim3(512, N_EXP, 2), dim3(256), 0, stream>>>(W1, W1t, W2, W2t);
  gather_cvt<<<dim3(MAXS), dim3(256), 0, stream>>>(moe_inp, cnt, btok, Xg);
  moe_gemm<0><<<dim3(2048), dim3(256), 0, stream>>>(
      Xg, W1t, b1, cnt, btok, bw, Hbuf, nullptr);
  moe_gemm<1><<<dim3(2048), dim3(256), 0, stream>>>(
      Hbuf, W2t, b2, cnt, btok, bw, nullptr, out);
}

// Round 2
// 333.231 us; speedup vs baseline: 1.0553x; 1.0553x over previous
//
#include <hip/hip_runtime.h>
#include <stdint.h>

#define T_TOK 2048
#define D_DIM 1024
#define H_DIM 2048
#define N_EXP 8
#define MAXS  4608   // max padded slots: 4096 + 8*63 = 4600 -> 4608

// workspace layout (bytes)
#define WS_CNT    0
#define WS_BTOK   256
#define WS_BW     (WS_BTOK + N_EXP*2048*4)
#define WS_XG     (WS_BW + N_EXP*2048*4)        // 16B aligned
#define WS_HBUF   (WS_XG + (size_t)MAXS*1024*2)
#define WS_W1T    (WS_HBUF + (size_t)MAXS*2048*2)
#define WS_W2T    (WS_W1T + (size_t)N_EXP*1024*2048*2)

typedef __bf16 bf16x8 __attribute__((ext_vector_type(8)));
typedef float  f32x4  __attribute__((ext_vector_type(4)));

__device__ __forceinline__ unsigned short f2bf(float f) {
  unsigned int u = __float_as_uint(f);
  u += 0x7fffu + ((u >> 16) & 1u);   // round-to-nearest-even
  return (unsigned short)(u >> 16);
}

// fast tanh-approx gelu: tanh(u) = sign(u)*(1-e^{-2|u|})/(1+e^{-2|u|})
// __expf -> v_exp_f32, rcpf -> v_rcp_f32. rel err ~1e-5, far below bf16 rounding.
__device__ __forceinline__ float gelu_tanh(float x) {
  const float u = 0.7978845608028654f * (x + 0.044715f * x * x * x);
  const float t = __expf(-2.0f * fabsf(u));
  const float th = (1.0f - t) * __builtin_amdgcn_rcpf(1.0f + t);
  return 0.5f * x * (1.0f + copysignf(th, u));
}

__global__ void zero_kernel(float4* __restrict__ out4, int* __restrict__ cnt) {
  int i = blockIdx.x * 256 + threadIdx.x;  // 2048 blocks * 256 * 4 floats = T*D
  out4[i] = make_float4(0.f, 0.f, 0.f, 0.f);
  if (blockIdx.x == 0 && threadIdx.x < N_EXP) cnt[threadIdx.x] = 0;
}

// one wave per token: logits = x @ Wg + bg; top-2; softmax; bucket scatter
__global__ void gate_kernel(const float* __restrict__ x, const float* __restrict__ Wg,
                            const float* __restrict__ bg, float* __restrict__ out_idx,
                            int* __restrict__ cnt, int* __restrict__ btok,
                            float* __restrict__ bw) {
  const int lane = threadIdx.x & 63;
  const int t = blockIdx.x * 4 + (threadIdx.x >> 6);
  float p[8];
#pragma unroll
  for (int i = 0; i < 8; ++i) p[i] = 0.f;
  const float* xr = x + (size_t)t * D_DIM;
  for (int i = lane; i < D_DIM; i += 64) {
    const float xv = xr[i];
    const float4 wa = ((const float4*)(Wg + i * 8))[0];
    const float4 wb = ((const float4*)(Wg + i * 8))[1];
    p[0] += xv * wa.x; p[1] += xv * wa.y; p[2] += xv * wa.z; p[3] += xv * wa.w;
    p[4] += xv * wb.x; p[5] += xv * wb.y; p[6] += xv * wb.z; p[7] += xv * wb.w;
  }
#pragma unroll
  for (int off = 32; off > 0; off >>= 1) {
#pragma unroll
    for (int i = 0; i < 8; ++i) p[i] += __shfl_xor(p[i], off);
  }
  if (lane == 0) {
#pragma unroll
    for (int i = 0; i < 8; ++i) p[i] += bg[i];
    int i0 = 0; float v0 = p[0];
#pragma unroll
    for (int i = 1; i < 8; ++i) if (p[i] > v0) { v0 = p[i]; i0 = i; }
    int i1 = -1; float v1 = -3.4e38f;
#pragma unroll
    for (int i = 0; i < 8; ++i) if (i != i0 && p[i] > v1) { v1 = p[i]; i1 = i; }
    const float ex = expf(v1 - v0);
    const float inv = 1.f / (1.f + ex);
    out_idx[t * 2 + 0] = (float)i0;
    out_idx[t * 2 + 1] = (float)i1;
    int s0 = atomicAdd(&cnt[i0], 1);
    btok[i0 * 2048 + s0] = t; bw[i0 * 2048 + s0] = inv;
    int s1 = atomicAdd(&cnt[i1], 1);
    btok[i1 * 2048 + s1] = t; bw[i1 * 2048 + s1] = ex * inv;
  }
}

// Both weight transposes in one launch. set 0: W1 [e][1024][2048] -> [e][2048][1024]
//                                      set 1: W2 [e][2048][1024] -> [e][1024][2048]
__global__ void transpose_cvt(const float* __restrict__ W1, unsigned short* __restrict__ W1t,
                              const float* __restrict__ W2, unsigned short* __restrict__ W2t) {
  const int set = blockIdx.z;
  const int e = blockIdx.y;
  const int lin = blockIdx.x;               // 0..511
  const int R = set ? H_DIM : D_DIM;
  const int C = set ? D_DIM : H_DIM;
  const int tx = set ? (lin & 15) : (lin & 31);
  const int ty = set ? (lin >> 4) : (lin >> 5);
  const float* in = (set ? W2 : W1) + (size_t)e * (D_DIM * H_DIM);
  unsigned short* out = (set ? W2t : W1t) + (size_t)e * (D_DIM * H_DIM);
  const int c0 = tx * 64, r0 = ty * 64;
  __shared__ float tile[64][68];
  const int tid = threadIdx.x;
#pragma unroll
  for (int p = 0; p < 4; ++p) {
    const int idx = p * 256 + tid;
    const int r = idx >> 4, c4 = idx & 15;
    *(float4*)&tile[r][c4 * 4] = *(const float4*)(in + (size_t)(r0 + r) * C + c0 + c4 * 4);
  }
  __syncthreads();
#pragma unroll
  for (int p = 0; p < 2; ++p) {
    const int idx = p * 256 + tid;
    const int oc = idx >> 3, seg = idx & 7;
    unsigned u[4];
#pragma unroll
    for (int j = 0; j < 4; ++j) {
      const unsigned lo = f2bf(tile[seg * 8 + 2 * j][oc]);
      const unsigned hi = f2bf(tile[seg * 8 + 2 * j + 1][oc]);
      u[j] = lo | (hi << 16);
    }
    *(uint4*)(out + (size_t)(c0 + oc) * R + r0 + seg * 8) = make_uint4(u[0], u[1], u[2], u[3]);
  }
}

// inline padded prefix over the 8 expert counts
__device__ __forceinline__ void expert_seg(const int* __restrict__ cnt, int e,
                                           int& base, int& ce, int& pcnt, int& total) {
  int off = 0; base = 0; ce = 0; pcnt = 0;
#pragma unroll
  for (int i = 0; i < N_EXP; ++i) {
    const int c = cnt[i];
    const int p = (c + 63) & ~63;
    if (i == e) { base = off; ce = c; pcnt = p; }
    off += p;
  }
  total = off;
}

// one block per padded slot row: gather routed token row fp32 -> bf16 (pad rows = 0)
__global__ void gather_cvt(const float* __restrict__ x, const int* __restrict__ cnt,
                           const int* __restrict__ btok, unsigned short* __restrict__ Xg) {
  const int s = blockIdx.x;
  int off = 0, e = -1, loc = 0, c_e = 0;
#pragma unroll
  for (int i = 0; i < N_EXP; ++i) {
    const int c = cnt[i];
    const int p = (c + 63) & ~63;
    if (e < 0 && s < off + p) { e = i; loc = s - off; c_e = c; }
    off += p;
  }
  if (e < 0) return;  // beyond total padded slots
  uint2* orow = (uint2*)(Xg + (size_t)s * D_DIM);
  if (loc < c_e) {
    const int t = btok[e * 2048 + loc];
    const float4 v = ((const float4*)(x + (size_t)t * D_DIM))[threadIdx.x];
    uint2 u;
    u.x = (unsigned)f2bf(v.x) | ((unsigned)f2bf(v.y) << 16);
    u.y = (unsigned)f2bf(v.z) | ((unsigned)f2bf(v.w) << 16);
    orow[threadIdx.x] = u;
  } else {
    orow[threadIdx.x] = make_uint2(0u, 0u);
  }
}

// MODE 0: Hbuf[s][n] = gelu(Xg[s] @ W1t[e]^T + b1[e])     (K=1024, N=2048, SK=1)
// MODE 1: out[tok]  += w_s * (Hbuf[s] @ W2t[e]^T + b2[e]) (K=2048, N=1024, SK=2, atomic)
// 64x128 tiles (4 waves 2x2, acc 2x4 each), double-buffered LDS, one barrier/iter.
// Grid 4096, XCD-swizzled: same-(n,e,ksl) m-tiles share blockIdx%8 -> one XCD.
// NOTE: 64-row M tiles deliberately (not 128): with M~4600 total, 128-row tiles
// halve active blocks -> occupancy 37%->20% and gemm 63.6->70.9us (measured R1).
template <int MODE>
__global__ void __launch_bounds__(256) moe_gemm(
    const unsigned short* __restrict__ A, const unsigned short* __restrict__ B,
    const float* __restrict__ bias, const int* __restrict__ cnt,
    const int* __restrict__ btok, const float* __restrict__ bw,
    unsigned short* __restrict__ Hout, float* __restrict__ out) {
  constexpr int K   = (MODE == 0) ? D_DIM : H_DIM;
  constexpr int SK  = (MODE == 0) ? 1 : 2;
  constexpr int KS  = K / SK;
  constexpr int NIT = KS / 32;

  const int lin = blockIdx.x;                 // 0..4095
  const int glo = lin & 7;
  const int mt  = (lin >> 3) & 31;            // up to 32 m-tiles of 64 rows
  const int g   = ((lin >> 8) << 3) | glo;    // 0..127
  int nt, e, ksl;
  if (MODE == 0) { nt = g & 15; e = g >> 4; ksl = 0; }
  else           { nt = g & 7;  e = (g >> 3) & 7; ksl = g >> 6; }

  int base, ce, pcnt, total;
  expert_seg(cnt, e, base, ce, pcnt, total);
  if (mt * 64 >= pcnt) return;
  const int row0 = base + mt * 64;
  const int n0 = nt * 128;

  __shared__ __align__(16) unsigned short As[2][64 * 32];
  __shared__ __align__(16) unsigned short Bs[2][128 * 32];

  const int tid = threadIdx.x;
  const int lane = tid & 63;
  const int wv = tid >> 6;
  const int wm = wv >> 1;
  const int wn = wv & 1;

  const unsigned short* Ab = A + (size_t)row0 * K + ksl * KS;
  const unsigned short* Bb = B + (size_t)e * ((size_t)H_DIM * D_DIM) + (size_t)n0 * K + ksl * KS;

  f32x4 acc[2][4];
#pragma unroll
  for (int i = 0; i < 2; ++i)
#pragma unroll
    for (int j = 0; j < 4; ++j) acc[i][j] = (f32x4)(0.0f);

  const int subr = lane >> 2;        // 0..15
  const int ks = (lane & 3) * 8;     // 0,8,16,24 halfs
  const int fr = lane & 15;
  const int kq = (lane >> 4) * 8;

  auto stage = [&](int kt, int b) {
    const int k0 = kt * 32;
    {  // A: 4 chunks of 16 rows, one per wave
      const int r = wv * 16 + subr;
      const unsigned short* ga = Ab + (size_t)r * K + (k0 + ks);
      __builtin_amdgcn_global_load_lds(
          (__attribute__((address_space(1))) void*)ga,
          (__attribute__((address_space(3))) void*)(As[b] + wv * 16 * 32), 16, 0, 0);
    }
#pragma unroll
    for (int it = 0; it < 2; ++it) {  // B: 8 chunks, two per wave
      const int ci = wv + it * 4;
      const int r = ci * 16 + subr;
      const unsigned short* gb = Bb + (size_t)r * K + (k0 + ks);
      __builtin_amdgcn_global_load_lds(
          (__attribute__((address_space(1))) void*)gb,
          (__attribute__((address_space(3))) void*)(Bs[b] + ci * 16 * 32), 16, 0, 0);
    }
  };

  stage(0, 0);
  for (int i = 0; i < NIT; ++i) {
    const int b = i & 1;
    __syncthreads();                  // drains prefetch into buf b; protects WAR on b^1
    if (i + 1 < NIT) stage(i + 1, b ^ 1);
    bf16x8 av[2], bv[4];
#pragma unroll
    for (int mi = 0; mi < 2; ++mi)
      av[mi] = *(const bf16x8*)(As[b] + (wm * 32 + mi * 16 + fr) * 32 + kq);
#pragma unroll
    for (int ni = 0; ni < 4; ++ni)
      bv[ni] = *(const bf16x8*)(Bs[b] + (wn * 64 + ni * 16 + fr) * 32 + kq);
#pragma unroll
    for (int mi = 0; mi < 2; ++mi)
#pragma unroll
      for (int ni = 0; ni < 4; ++ni)
        acc[mi][ni] = __builtin_amdgcn_mfma_f32_16x16x32_bf16(av[mi], bv[ni], acc[mi][ni], 0, 0, 0);
  }

  if (MODE == 0) {
    const float* bb = bias + (size_t)e * H_DIM + n0;
#pragma unroll
    for (int mi = 0; mi < 2; ++mi) {
      const int rb = wm * 32 + mi * 16 + (lane >> 4) * 4;
#pragma unroll
      for (int r = 0; r < 4; ++r) {
        unsigned short* hp = Hout + (size_t)(row0 + rb + r) * H_DIM + n0;
#pragma unroll
        for (int ni = 0; ni < 4; ++ni) {
          const int col = wn * 64 + ni * 16 + fr;
          hp[col] = f2bf(gelu_tanh(acc[mi][ni][r] + bb[col]));
        }
      }
    }
  } else {
    const float* bb = bias + (size_t)e * D_DIM + n0;
#pragma unroll
    for (int mi = 0; mi < 2; ++mi) {
      const int rb = wm * 32 + mi * 16 + (lane >> 4) * 4;
#pragma unroll
      for (int r = 0; r < 4; ++r) {
        const int local = mt * 64 + rb + r;
        if (local < ce) {
          const int tok = btok[e * 2048 + local];
          const float w = bw[e * 2048 + local];
          float* op = out + (size_t)tok * D_DIM + n0;
#pragma unroll
          for (int ni = 0; ni < 4; ++ni) {
            const int col = wn * 64 + ni * 16 + fr;
            const float bias_once = (ksl == 0) ? bb[col] : 0.f;
            atomicAdd(op + col, w * (acc[mi][ni][r] + bias_once));
          }
        }
      }
    }
  }
}

extern "C" void kernel_launch(void* const* d_in, const int* in_sizes, int n_in,
                              void* d_out, int out_size, void* d_ws, size_t ws_size,
                              hipStream_t stream) {
  const float* moe_inp = (const float*)d_in[0];
  const float* Wg = (const float*)d_in[1];
  const float* bg = (const float*)d_in[2];
  const float* W1 = (const float*)d_in[3];
  const float* b1 = (const float*)d_in[4];
  const float* W2 = (const float*)d_in[5];
  const float* b2 = (const float*)d_in[6];
  float* out = (float*)d_out;

  char* ws = (char*)d_ws;
  int* cnt  = (int*)(ws + WS_CNT);
  int* btok = (int*)(ws + WS_BTOK);
  float* bw = (float*)(ws + WS_BW);
  unsigned short* Xg   = (unsigned short*)(ws + WS_XG);
  unsigned short* Hbuf = (unsigned short*)(ws + WS_HBUF);
  unsigned short* W1t  = (unsigned short*)(ws + WS_W1T);
  unsigned short* W2t  = (unsigned short*)(ws + WS_W2T);

  zero_kernel<<<dim3(2048), dim3(256), 0, stream>>>((float4*)out, cnt);
  gate_kernel<<<dim3(T_TOK / 4), dim3(256), 0, stream>>>(moe_inp, Wg, bg,
                                                         out + (size_t)T_TOK * D_DIM,
                                                         cnt, btok, bw);
  transpose_cvt<<<dim3(512, N_EXP, 2), dim3(256), 0, stream>>>(W1, W1t, W2, W2t);
  gather_cvt<<<dim3(MAXS), dim3(256), 0, stream>>>(moe_inp, cnt, btok, Xg);
  moe_gemm<0><<<dim3(4096), dim3(256), 0, stream>>>(
      Xg, W1t, b1, cnt, btok, bw, Hbuf, nullptr);
  moe_gemm<1><<<dim3(4096), dim3(256), 0, stream>>>(
      Hbuf, W2t, b2, cnt, btok, bw, nullptr, out);
}

// Round 3
// 318.450 us; speedup vs baseline: 1.1042x; 1.0464x over previous
//
#include <hip/hip_runtime.h>
#include <stdint.h>

#define T_TOK 2048
#define D_DIM 1024
#define H_DIM 2048
#define N_EXP 8
#define MAXS  4608   // max padded slots: 4096 + 8*63 = 4600 -> 4608

// workspace layout (bytes)
#define WS_CNT    0
#define WS_BTOK   256
#define WS_BW     (WS_BTOK + N_EXP*2048*4)
#define WS_XG     (WS_BW + N_EXP*2048*4)        // 16B aligned
#define WS_HBUF   (WS_XG + (size_t)MAXS*1024*2)
#define WS_W1T    (WS_HBUF + (size_t)MAXS*2048*2)
#define WS_W2T    (WS_W1T + (size_t)N_EXP*1024*2048*2)

typedef __bf16 bf16x8 __attribute__((ext_vector_type(8)));
typedef float  f32x4  __attribute__((ext_vector_type(4)));

__device__ __forceinline__ unsigned short f2bf(float f) {
  unsigned int u = __float_as_uint(f);
  u += 0x7fffu + ((u >> 16) & 1u);   // round-to-nearest-even
  return (unsigned short)(u >> 16);
}

// fast tanh-approx gelu: tanh(u) = sign(u)*(1-e^{-2|u|})/(1+e^{-2|u|})
__device__ __forceinline__ float gelu_tanh(float x) {
  const float u = 0.7978845608028654f * (x + 0.044715f * x * x * x);
  const float t = __expf(-2.0f * fabsf(u));
  const float th = (1.0f - t) * __builtin_amdgcn_rcpf(1.0f + t);
  return 0.5f * x * (1.0f + copysignf(th, u));
}

// ---------------- device bodies (shared by fused kernels) ----------------

// 64x64 fp32->bf16 transpose tile. in: rows of Cin floats; out: rows of Rout bf16.
__device__ __forceinline__ void transpose_body(const float* __restrict__ in,
                                               unsigned short* __restrict__ out,
                                               int Rout, int Cin, int tx, int ty,
                                               void* smem_) {
  float (*tile)[68] = (float (*)[68])smem_;   // 64x68 fp32 = 17408 B
  const int c0 = tx * 64, r0 = ty * 64;
  const int tid = threadIdx.x;
#pragma unroll
  for (int p = 0; p < 4; ++p) {
    const int idx = p * 256 + tid;
    const int r = idx >> 4, c4 = idx & 15;
    *(float4*)&tile[r][c4 * 4] = *(const float4*)(in + (size_t)(r0 + r) * Cin + c0 + c4 * 4);
  }
  __syncthreads();
#pragma unroll
  for (int p = 0; p < 2; ++p) {
    const int idx = p * 256 + tid;
    const int oc = idx >> 3, seg = idx & 7;
    unsigned u[4];
#pragma unroll
    for (int j = 0; j < 4; ++j) {
      const unsigned lo = f2bf(tile[seg * 8 + 2 * j][oc]);
      const unsigned hi = f2bf(tile[seg * 8 + 2 * j + 1][oc]);
      u[j] = lo | (hi << 16);
    }
    *(uint4*)(out + (size_t)(c0 + oc) * Rout + r0 + seg * 8) = make_uint4(u[0], u[1], u[2], u[3]);
  }
}

// one wave per token: logits = x @ Wg + bg; top-2; softmax; bucket scatter
__device__ __forceinline__ void gate_body(int t, const float* __restrict__ x,
                                          const float* __restrict__ Wg,
                                          const float* __restrict__ bg,
                                          float* __restrict__ out_idx,
                                          int* __restrict__ cnt, int* __restrict__ btok,
                                          float* __restrict__ bw) {
  const int lane = threadIdx.x & 63;
  float p[8];
#pragma unroll
  for (int i = 0; i < 8; ++i) p[i] = 0.f;
  const float* xr = x + (size_t)t * D_DIM;
  for (int i = lane; i < D_DIM; i += 64) {
    const float xv = xr[i];
    const float4 wa = ((const float4*)(Wg + i * 8))[0];
    const float4 wb = ((const float4*)(Wg + i * 8))[1];
    p[0] += xv * wa.x; p[1] += xv * wa.y; p[2] += xv * wa.z; p[3] += xv * wa.w;
    p[4] += xv * wb.x; p[5] += xv * wb.y; p[6] += xv * wb.z; p[7] += xv * wb.w;
  }
#pragma unroll
  for (int off = 32; off > 0; off >>= 1) {
#pragma unroll
    for (int i = 0; i < 8; ++i) p[i] += __shfl_xor(p[i], off);
  }
  if (lane == 0) {
#pragma unroll
    for (int i = 0; i < 8; ++i) p[i] += bg[i];
    int i0 = 0; float v0 = p[0];
#pragma unroll
    for (int i = 1; i < 8; ++i) if (p[i] > v0) { v0 = p[i]; i0 = i; }
    int i1 = -1; float v1 = -3.4e38f;
#pragma unroll
    for (int i = 0; i < 8; ++i) if (i != i0 && p[i] > v1) { v1 = p[i]; i1 = i; }
    const float ex = expf(v1 - v0);
    const float inv = 1.f / (1.f + ex);
    out_idx[t * 2 + 0] = (float)i0;
    out_idx[t * 2 + 1] = (float)i1;
    int s0 = atomicAdd(&cnt[i0], 1);
    btok[i0 * 2048 + s0] = t; bw[i0 * 2048 + s0] = inv;
    int s1 = atomicAdd(&cnt[i1], 1);
    btok[i1 * 2048 + s1] = t; bw[i1 * 2048 + s1] = ex * inv;
  }
}

// inline padded prefix over the 8 expert counts
__device__ __forceinline__ void expert_seg(const int* __restrict__ cnt, int e,
                                           int& base, int& ce, int& pcnt, int& total) {
  int off = 0; base = 0; ce = 0; pcnt = 0;
#pragma unroll
  for (int i = 0; i < N_EXP; ++i) {
    const int c = cnt[i];
    const int p = (c + 63) & ~63;
    if (i == e) { base = off; ce = c; pcnt = p; }
    off += p;
  }
  total = off;
}

// MODE 0: Hbuf[s][n] = gelu(Xg[s] @ W1t[e]^T + b1[e])     (K=1024, N=2048, SK=1)
// MODE 1: out[tok]  += w_s * (Hbuf[s] @ W2t[e]^T + b2[e]) (K=2048, N=1024, SK=2, atomic)
// 64x128 tiles (4 waves 2x2, acc 2x4 each), double-buffered LDS, one barrier/iter.
// 64-row M tiles deliberately (not 128): with M~4600 total, 128-row tiles halve
// active blocks -> occupancy 37%->20% and gemm 63.6->70.9us (measured R1).
template <int MODE>
__device__ __forceinline__ void gemm_body(
    int lin, const unsigned short* __restrict__ A, const unsigned short* __restrict__ B,
    const float* __restrict__ bias, const int* __restrict__ cnt,
    const int* __restrict__ btok, const float* __restrict__ bw,
    unsigned short* __restrict__ Hout, float* __restrict__ out, void* smem_) {
  constexpr int K   = (MODE == 0) ? D_DIM : H_DIM;
  constexpr int SK  = (MODE == 0) ? 1 : 2;
  constexpr int KS  = K / SK;
  constexpr int NIT = KS / 32;

  const int glo = lin & 7;
  const int mt  = (lin >> 3) & 31;            // up to 32 m-tiles of 64 rows
  const int g   = ((lin >> 8) << 3) | glo;    // 0..127
  int nt, e, ksl;
  if (MODE == 0) { nt = g & 15; e = g >> 4; ksl = 0; }
  else           { nt = g & 7;  e = (g >> 3) & 7; ksl = g >> 6; }

  int base, ce, pcnt, total;
  expert_seg(cnt, e, base, ce, pcnt, total);
  if (mt * 64 >= pcnt) return;
  const int row0 = base + mt * 64;
  const int n0 = nt * 128;

  unsigned short (*As)[64 * 32] = (unsigned short (*)[64 * 32])smem_;              // 8 KB
  unsigned short (*Bs)[128 * 32] = (unsigned short (*)[128 * 32])((char*)smem_ + 8192);  // 16 KB

  const int tid = threadIdx.x;
  const int lane = tid & 63;
  const int wv = tid >> 6;
  const int wm = wv >> 1;
  const int wn = wv & 1;

  const unsigned short* Ab = A + (size_t)row0 * K + ksl * KS;
  const unsigned short* Bb = B + (size_t)e * ((size_t)H_DIM * D_DIM) + (size_t)n0 * K + ksl * KS;

  f32x4 acc[2][4];
#pragma unroll
  for (int i = 0; i < 2; ++i)
#pragma unroll
    for (int j = 0; j < 4; ++j) acc[i][j] = (f32x4)(0.0f);

  const int subr = lane >> 2;        // 0..15
  const int ks = (lane & 3) * 8;     // 0,8,16,24 halfs
  const int fr = lane & 15;
  const int kq = (lane >> 4) * 8;

  auto stage = [&](int kt, int b) {
    const int k0 = kt * 32;
    {  // A: 4 chunks of 16 rows, one per wave
      const int r = wv * 16 + subr;
      const unsigned short* ga = Ab + (size_t)r * K + (k0 + ks);
      __builtin_amdgcn_global_load_lds(
          (__attribute__((address_space(1))) void*)ga,
          (__attribute__((address_space(3))) void*)(As[b] + wv * 16 * 32), 16, 0, 0);
    }
#pragma unroll
    for (int it = 0; it < 2; ++it) {  // B: 8 chunks, two per wave
      const int ci = wv + it * 4;
      const int r = ci * 16 + subr;
      const unsigned short* gb = Bb + (size_t)r * K + (k0 + ks);
      __builtin_amdgcn_global_load_lds(
          (__attribute__((address_space(1))) void*)gb,
          (__attribute__((address_space(3))) void*)(Bs[b] + ci * 16 * 32), 16, 0, 0);
    }
  };

  stage(0, 0);
  for (int i = 0; i < NIT; ++i) {
    const int b = i & 1;
    __syncthreads();                  // drains prefetch into buf b; protects WAR on b^1
    if (i + 1 < NIT) stage(i + 1, b ^ 1);
    bf16x8 av[2], bv[4];
#pragma unroll
    for (int mi = 0; mi < 2; ++mi)
      av[mi] = *(const bf16x8*)(As[b] + (wm * 32 + mi * 16 + fr) * 32 + kq);
#pragma unroll
    for (int ni = 0; ni < 4; ++ni)
      bv[ni] = *(const bf16x8*)(Bs[b] + (wn * 64 + ni * 16 + fr) * 32 + kq);
#pragma unroll
    for (int mi = 0; mi < 2; ++mi)
#pragma unroll
      for (int ni = 0; ni < 4; ++ni)
        acc[mi][ni] = __builtin_amdgcn_mfma_f32_16x16x32_bf16(av[mi], bv[ni], acc[mi][ni], 0, 0, 0);
  }

  if (MODE == 0) {
    const float* bb = bias + (size_t)e * H_DIM + n0;
#pragma unroll
    for (int mi = 0; mi < 2; ++mi) {
      const int rb = wm * 32 + mi * 16 + (lane >> 4) * 4;
#pragma unroll
      for (int r = 0; r < 4; ++r) {
        unsigned short* hp = Hout + (size_t)(row0 + rb + r) * H_DIM + n0;
#pragma unroll
        for (int ni = 0; ni < 4; ++ni) {
          const int col = wn * 64 + ni * 16 + fr;
          hp[col] = f2bf(gelu_tanh(acc[mi][ni][r] + bb[col]));
        }
      }
    }
  } else {
    const float* bb = bias + (size_t)e * D_DIM + n0;
#pragma unroll
    for (int mi = 0; mi < 2; ++mi) {
      const int rb = wm * 32 + mi * 16 + (lane >> 4) * 4;
#pragma unroll
      for (int r = 0; r < 4; ++r) {
        const int local = mt * 64 + rb + r;
        if (local < ce) {
          const int tok = btok[e * 2048 + local];
          const float w = bw[e * 2048 + local];
          float* op = out + (size_t)tok * D_DIM + n0;
#pragma unroll
          for (int ni = 0; ni < 4; ++ni) {
            const int col = wn * 64 + ni * 16 + fr;
            const float bias_once = (ksl == 0) ? bb[col] : 0.f;
            atomicAdd(op + col, w * (acc[mi][ni][r] + bias_once));
          }
        }
      }
    }
  }
}

// ---------------- fused kernels ----------------

// blocks [0,2048): zero out; [2048,2560): gate (4 tok/blk); [2560,6656): W1 transpose.
// All three roles independent. cnt must be zeroed BEFORE this kernel (memset node):
// intra-grid ordering is undefined, so cnt-zero cannot share a kernel with gate atomics.
__global__ void __launch_bounds__(256) prep_kernel(
    const float* __restrict__ x, const float* __restrict__ Wg,
    const float* __restrict__ bg, const float* __restrict__ W1,
    float* __restrict__ out, int* __restrict__ cnt, int* __restrict__ btok,
    float* __restrict__ bw, unsigned short* __restrict__ W1t) {
  __shared__ __align__(16) char smem[17408];
  const int bid = blockIdx.x;
  if (bid < 2048) {
    ((float4*)out)[bid * 256 + threadIdx.x] = make_float4(0.f, 0.f, 0.f, 0.f);
  } else if (bid < 2560) {
    gate_body((bid - 2048) * 4 + (threadIdx.x >> 6), x, Wg, bg,
              out + (size_t)T_TOK * D_DIM, cnt, btok, bw);
  } else {
    const int lin = bid - 2560;          // 0..4095
    const int e = lin >> 9, l9 = lin & 511;
    // W1 [1024][2048] -> W1t [2048][1024]: Rout=1024, Cin=2048, 32 tx x 16 ty
    transpose_body(W1 + (size_t)e * (D_DIM * H_DIM), W1t + (size_t)e * (D_DIM * H_DIM),
                   D_DIM, H_DIM, l9 & 31, l9 >> 5, smem);
  }
}

// one block per padded slot row: gather routed token row fp32 -> bf16 (pad rows = 0)
__global__ void gather_cvt(const float* __restrict__ x, const int* __restrict__ cnt,
                           const int* __restrict__ btok, unsigned short* __restrict__ Xg) {
  const int s = blockIdx.x;
  int off = 0, e = -1, loc = 0, c_e = 0;
#pragma unroll
  for (int i = 0; i < N_EXP; ++i) {
    const int c = cnt[i];
    const int p = (c + 63) & ~63;
    if (e < 0 && s < off + p) { e = i; loc = s - off; c_e = c; }
    off += p;
  }
  if (e < 0) return;
  uint2* orow = (uint2*)(Xg + (size_t)s * D_DIM);
  if (loc < c_e) {
    const int t = btok[e * 2048 + loc];
    const float4 v = ((const float4*)(x + (size_t)t * D_DIM))[threadIdx.x];
    uint2 u;
    u.x = (unsigned)f2bf(v.x) | ((unsigned)f2bf(v.y) << 16);
    u.y = (unsigned)f2bf(v.z) | ((unsigned)f2bf(v.w) << 16);
    orow[threadIdx.x] = u;
  } else {
    orow[threadIdx.x] = make_uint2(0u, 0u);
  }
}

// blocks [0,4096): moe_gemm<0>; [4096,8192): W2 transpose (needed only by gemm1).
// gemm0 uses ~25% HBM BW and ~37% wave slots -> the memory-bound transpose rides
// in the idle BW/slots instead of serializing as its own ~25us dispatch.
// LDS unioned in one 24KB block so gemm occupancy is unchanged.
__global__ void __launch_bounds__(256) gemm0_w2t(
    const unsigned short* __restrict__ Xg, const unsigned short* __restrict__ W1t,
    const float* __restrict__ b1, const int* __restrict__ cnt,
    const int* __restrict__ btok, const float* __restrict__ bw,
    unsigned short* __restrict__ Hbuf, const float* __restrict__ W2,
    unsigned short* __restrict__ W2t) {
  __shared__ __align__(16) char smem[24576];
  if (blockIdx.x < 4096) {
    gemm_body<0>(blockIdx.x, Xg, W1t, b1, cnt, btok, bw, Hbuf, nullptr, smem);
  } else {
    const int lin = blockIdx.x - 4096;   // 0..4095
    const int e = lin >> 9, l9 = lin & 511;
    // W2 [2048][1024] -> W2t [1024][2048]: Rout=2048, Cin=1024, 16 tx x 32 ty
    transpose_body(W2 + (size_t)e * (D_DIM * H_DIM), W2t + (size_t)e * (D_DIM * H_DIM),
                   H_DIM, D_DIM, l9 & 15, l9 >> 4, smem);
  }
}

__global__ void __launch_bounds__(256) moe_gemm1(
    const unsigned short* __restrict__ Hbuf, const unsigned short* __restrict__ W2t,
    const float* __restrict__ b2, const int* __restrict__ cnt,
    const int* __restrict__ btok, const float* __restrict__ bw,
    float* __restrict__ out) {
  __shared__ __align__(16) char smem[24576];
  gemm_body<1>(blockIdx.x, Hbuf, W2t, b2, cnt, btok, bw, nullptr, out, smem);
}

extern "C" void kernel_launch(void* const* d_in, const int* in_sizes, int n_in,
                              void* d_out, int out_size, void* d_ws, size_t ws_size,
                              hipStream_t stream) {
  const float* moe_inp = (const float*)d_in[0];
  const float* Wg = (const float*)d_in[1];
  const float* bg = (const float*)d_in[2];
  const float* W1 = (const float*)d_in[3];
  const float* b1 = (const float*)d_in[4];
  const float* W2 = (const float*)d_in[5];
  const float* b2 = (const float*)d_in[6];
  float* out = (float*)d_out;

  char* ws = (char*)d_ws;
  int* cnt  = (int*)(ws + WS_CNT);
  int* btok = (int*)(ws + WS_BTOK);
  float* bw = (float*)(ws + WS_BW);
  unsigned short* Xg   = (unsigned short*)(ws + WS_XG);
  unsigned short* Hbuf = (unsigned short*)(ws + WS_HBUF);
  unsigned short* W1t  = (unsigned short*)(ws + WS_W1T);
  unsigned short* W2t  = (unsigned short*)(ws + WS_W2T);

  hipMemsetAsync(cnt, 0, 256, stream);   // gate atomics need cnt=0 (capturable memset node)
  prep_kernel<<<dim3(6656), dim3(256), 0, stream>>>(moe_inp, Wg, bg, W1,
                                                    out, cnt, btok, bw, W1t);
  gather_cvt<<<dim3(MAXS), dim3(256), 0, stream>>>(moe_inp, cnt, btok, Xg);
  gemm0_w2t<<<dim3(8192), dim3(256), 0, stream>>>(Xg, W1t, b1, cnt, btok, bw,
                                                  Hbuf, W2, W2t);
  moe_gemm1<<<dim3(4096), dim3(256), 0, stream>>>(Hbuf, W2t, b2, cnt, btok, bw, out);
}